// Round 5
// baseline (1148.794 us; speedup 1.0000x reference)
//
#include <hip/hip_runtime.h>

#define B_  8
#define LV_ 4096
#define D_  256
#define N_  2048
#define P_  32

typedef float v4f __attribute__((ext_vector_type(4)));  // native vec for nontemporal store

// Pass 1: counting-sort box ids by batch into order[] (d_ws). Intra-batch
// order is atomic-nondeterministic -- only affects scheduling locality, not
// results (each box writes its own output region).
__global__ __launch_bounds__(256) void build_order_kernel(
    const int* __restrict__ batch_idx, int* __restrict__ order)
{
    __shared__ int cnt[B_], cur[B_];
    const int tid = threadIdx.x;
    if (tid < B_) cnt[tid] = 0;
    __syncthreads();
    for (int n = tid; n < N_; n += 256) atomicAdd(&cnt[batch_idx[n]], 1);
    __syncthreads();
    if (tid == 0) {
        int s = 0;
        for (int b = 0; b < B_; ++b) { cur[b] = s; s += cnt[b]; }
    }
    __syncthreads();
    for (int n = tid; n < N_; n += 256)
        order[atomicAdd(&cur[batch_idx[n]], 1)] = n;
}

// Pass 2: one 64-lane wave per (box, bin), slots ordered batch-major so the
// ~7k co-resident waves span <1 batch => each XCD's 4 MiB L2 holds the active
// feat slice (per-batch slice = 4096*256*4B = exactly 4 MiB). Lane l owns
// channels [4l,4l+4). Row-walk register reuse keeps loads at ~1 row/sample.
// No LDS, no atomics, no XCD swizzle (round-2 lesson: go WITH dispatch order).
__global__ __launch_bounds__(64) void roi_align1d_kernel(
    const float* __restrict__ feat,       // [B, LV, D]
    const float* __restrict__ boxes,      // [N, 2]
    const int*   __restrict__ batch_idx,  // [N]
    const int*   __restrict__ order,      // [N] sorted by batch
    float*       __restrict__ out)        // [N, P, D]
{
    const int slot = blockIdx.x;          // batch-major work order
    const int n    = order[slot >> 5];
    const int p    = slot & (P_ - 1);
    const int lane = threadIdx.x;

    const float y1    = boxes[2 * n];
    const float y2    = boxes[2 * n + 1];
    const float bin_h = (y2 - y1) * (1.0f / (float)P_);
    const int   gh    = (int)ceilf(bin_h);
    const int   cntk  = gh > 1 ? gh : 1;
    const float sub   = bin_h / (float)cntk;
    const float inv_c = 1.0f / (float)cntk;
    const float boff  = (y1 - 0.5f) + (float)p * bin_h;

    const float4* frow = (const float4*)feat + (long)batch_idx[n] * (LV_ * (D_ / 4)) + lane;

    float4 acc = make_float4(0.f, 0.f, 0.f, 0.f);
    float4 vlo = acc, vhi = acc;
    int cur_lo = -1000;

    for (int g = 0; g < gh; ++g) {
        const float y  = fmaf((float)g + 0.5f, sub, boff);
        // valid-check dropped: y in [-0.5, y2-0.5] subset of [-1, LV] always.
        const float yc = fmaxf(y, 0.0f);
        int lo = (int)floorf(yc);
        lo = lo < LV_ - 1 ? lo : LV_ - 1;                  // hi_case clamp
        const int   hi = lo + 1 < LV_ ? lo + 1 : LV_ - 1;
        const float ly = (lo < LV_ - 1) ? yc - (float)lo : 0.0f;
        const float w0 = 1.0f - ly;

        if (lo != cur_lo) {               // wave-uniform; lo steps by 0/1 within a box
            vlo = (lo == cur_lo + 1) ? vhi : frow[lo * (D_ / 4)];
            vhi = (hi != lo) ? frow[hi * (D_ / 4)] : vlo;
            cur_lo = lo;
        }

        acc.x = fmaf(w0, vlo.x, acc.x);
        acc.y = fmaf(w0, vlo.y, acc.y);
        acc.z = fmaf(w0, vlo.z, acc.z);
        acc.w = fmaf(w0, vlo.w, acc.w);
        acc.x = fmaf(ly, vhi.x, acc.x);
        acc.y = fmaf(ly, vhi.y, acc.y);
        acc.z = fmaf(ly, vhi.z, acc.z);
        acc.w = fmaf(ly, vhi.w, acc.w);
    }

    v4f res;
    res.x = acc.x * inv_c;
    res.y = acc.y * inv_c;
    res.z = acc.z * inv_c;
    res.w = acc.w * inv_c;

    // Nontemporal: 67 MB output stream must not evict the L2-resident feat.
    v4f* op = (v4f*)out + ((long)n * P_ + p) * (D_ / 4) + lane;
    __builtin_nontemporal_store(res, op);
}

extern "C" void kernel_launch(void* const* d_in, const int* in_sizes, int n_in,
                              void* d_out, int out_size, void* d_ws, size_t ws_size,
                              hipStream_t stream) {
    const float* feat      = (const float*)d_in[0];
    const float* boxes     = (const float*)d_in[1];
    const int*   batch_idx = (const int*)d_in[2];
    float*       out       = (float*)d_out;
    int*         order     = (int*)d_ws;    // N_ ints

    build_order_kernel<<<1, 256, 0, stream>>>(batch_idx, order);
    roi_align1d_kernel<<<N_ * P_, 64, 0, stream>>>(feat, boxes, batch_idx, order, out);
}

// Round 6
// 276.108 us; speedup vs baseline: 4.1607x; 4.1607x over previous
//
#include <hip/hip_runtime.h>

#define B_  8
#define LV_ 4096
#define D_  256
#define N_  2048
#define P_  32

typedef float v4f __attribute__((ext_vector_type(4)));

// Pass 1: counting-sort box ids by batch into order[] (d_ws) for XCD-L2 locality.
__global__ __launch_bounds__(256) void build_order_kernel(
    const int* __restrict__ batch_idx, int* __restrict__ order)
{
    __shared__ int cnt[B_], cur[B_];
    const int tid = threadIdx.x;
    if (tid < B_) cnt[tid] = 0;
    __syncthreads();
    for (int n = tid; n < N_; n += 256) atomicAdd(&cnt[batch_idx[n]], 1);
    __syncthreads();
    if (tid == 0) {
        int s = 0;
        for (int b = 0; b < B_; ++b) { cur[b] = s; s += cnt[b]; }
    }
    __syncthreads();
    for (int n = tid; n < N_; n += 256)
        order[atomicAdd(&cur[batch_idx[n]], 1)] = n;
}

// Pass 2: one wave per (box, bin). ANALYTIC ROW WEIGHTS: instead of the serial
// per-sample row walk (1 outstanding load/wave -> latency-product wall at
// ~2.6 TB/s), iterate over the contiguous row range [r_first, r_last] with the
// closed-form total weight each row receives from the uniform sample grid:
//   g(r) = first sample with y_g >= r ;  m = g(r+1)-g(r)
//   S_r  = sum of ly over that interval = m*(y_{g0}-r) + sub*m*(m-1)/2
//   W(r) = m - S_r + S_{r-1}
// Row loads are at sequential addresses with no data dependency -> compiler
// keeps many in flight. Edge rows (0-clamp, hi_case at LV-1) peeled.
__global__ __launch_bounds__(64) void roi_rows_kernel(
    const float* __restrict__ feat,       // [B, LV, D]
    const float* __restrict__ boxes,      // [N, 2]
    const int*   __restrict__ batch_idx,  // [N]
    const int*   __restrict__ order,      // [N] sorted by batch
    float*       __restrict__ out)        // [N, P, D]
{
    const int slot = blockIdx.x;
    const int n    = order[slot >> 5];
    const int p    = slot & (P_ - 1);
    const int lane = threadIdx.x;

    const float y1    = boxes[2 * n];
    const float y2    = boxes[2 * n + 1];
    const float bin_h = (y2 - y1) * (1.0f / (float)P_);
    const int   gh    = (int)ceilf(bin_h);

    const float4* frow = (const float4*)feat + (long)batch_idx[n] * (LV_ * (D_ / 4)) + lane;

    float4 acc = make_float4(0.f, 0.f, 0.f, 0.f);

    if (gh >= 1) {
        const float cntf    = (float)gh;
        const float sub     = bin_h / cntf;
        const float inv_sub = 1.0f / sub;                 // inf ok: boundaries clamped
        const float boff    = (y1 - 0.5f) + (float)p * bin_h;

        const float y0    = fmaf(0.5f, sub, boff);
        const float ylast = fmaf(cntf - 0.5f, sub, boff);
        int r_first  = (int)floorf(fmaxf(y0, 0.0f));
        r_first      = r_first < LV_ - 1 ? r_first : LV_ - 1;
        int r_lastlo = (int)floorf(fmaxf(ylast, 0.0f));
        r_lastlo     = r_lastlo < LV_ - 1 ? r_lastlo : LV_ - 1;
        const int r_last = (r_lastlo + 1 < LV_) ? r_lastlo + 1 : LV_ - 1;

        float S_prev = 0.0f;
        float gprev  = 0.0f;
        int   r      = r_first;

        if (r_first == 0) {                               // peel row 0 (y<0 clamp: weight 1)
            float4 v = frow[0];
            float t1 = fmaf(1.0f - boff, inv_sub, -0.5f);
            float g1 = fminf(fmaxf(ceilf(t1), 0.0f), cntf);
            float tz = fmaf(-boff, inv_sub, -0.5f);
            float gz = fminf(fmaxf(ceilf(tz), 0.0f), g1); // NaN (0*inf) -> 0 via fmaxf
            float kz = g1 - gz;                           // normal (y>=0) sample count
            float yz = fmaf(gz + 0.5f, sub, boff);
            float S  = kz * yz + sub * kz * (kz - 1.0f) * 0.5f;
            float W  = g1 - S;                            // clamped samples contribute 1 each
            acc.x = fmaf(W, v.x, acc.x);
            acc.y = fmaf(W, v.y, acc.y);
            acc.z = fmaf(W, v.z, acc.z);
            acc.w = fmaf(W, v.w, acc.w);
            S_prev = S; gprev = g1; r = 1;
        }

        const int r_main_end = (r_last < LV_ - 1) ? r_last : LV_ - 2;
        for (; r <= r_main_end; ++r) {                    // main: independent row loads
            float4 v = frow[r * (D_ / 4)];
            float t  = fmaf((float)(r + 1) - boff, inv_sub, -0.5f);
            float gn = fminf(fmaxf(ceilf(t), gprev), cntf);
            float mf = gn - gprev;
            float yg = fmaf(gprev + 0.5f, sub, boff);
            float S  = mf * (yg - (float)r) + sub * mf * (mf - 1.0f) * 0.5f;
            float W  = mf - S + S_prev;
            acc.x = fmaf(W, v.x, acc.x);
            acc.y = fmaf(W, v.y, acc.y);
            acc.z = fmaf(W, v.z, acc.z);
            acc.w = fmaf(W, v.w, acc.w);
            S_prev = S; gprev = gn;
        }

        if (r_last == LV_ - 1 && r <= r_last) {           // peel hi_case row (ly forced 0)
            float4 v = frow[(LV_ - 1) * (D_ / 4)];
            float mf = cntf - gprev;                      // all remaining samples, weight 1
            float W  = mf + S_prev;
            acc.x = fmaf(W, v.x, acc.x);
            acc.y = fmaf(W, v.y, acc.y);
            acc.z = fmaf(W, v.z, acc.z);
            acc.w = fmaf(W, v.w, acc.w);
        }
    }

    const float inv_c = 1.0f / (float)(gh > 1 ? gh : 1);
    v4f res;
    res.x = acc.x * inv_c;
    res.y = acc.y * inv_c;
    res.z = acc.z * inv_c;
    res.w = acc.w * inv_c;
    v4f* op = (v4f*)out + ((long)n * P_ + p) * (D_ / 4) + lane;
    __builtin_nontemporal_store(res, op);
}

extern "C" void kernel_launch(void* const* d_in, const int* in_sizes, int n_in,
                              void* d_out, int out_size, void* d_ws, size_t ws_size,
                              hipStream_t stream) {
    const float* feat      = (const float*)d_in[0];
    const float* boxes     = (const float*)d_in[1];
    const int*   batch_idx = (const int*)d_in[2];
    float*       out       = (float*)d_out;
    int*         order     = (int*)d_ws;    // N_ ints

    build_order_kernel<<<1, 256, 0, stream>>>(batch_idx, order);
    roi_rows_kernel<<<N_ * P_, 64, 0, stream>>>(feat, boxes, batch_idx, order, out);
}